// Round 5
// baseline (76.991 us; speedup 1.0000x reference)
//
#include <hip/hip_runtime.h>
#include <hip/hip_bf16.h>

// Problem constants (B,S,H,P) = (512, 256, 768, 32)
#define B_  512
#define S_  256
#define H_  768
#define P_  32
#define K1_ 2304   // 3H
#define K2_ 1536   // 2H
#define N_  768
#define M_  512
#define CVT_BLOCKS 128

typedef __attribute__((ext_vector_type(8))) short bf16x8v;
typedef __attribute__((ext_vector_type(8))) unsigned short u16x8;
typedef __attribute__((ext_vector_type(4))) float f32x4v;

__device__ inline unsigned short bfb(float x) {
  __hip_bfloat16 h = __float2bfloat16(x);  // RNE
  return *reinterpret_cast<unsigned short*>(&h);
}

// ---------------------------------------------------------------------------
// Kernel 1 (fused):
//   blocks [0,2B): (batch,tensor) mean-pool + concat -> row-major bf16 A
//                  Ab1[b][0:768)=pooled_proc [768:1536)=proc row0 [1536:2304)=phys row0
//                  Ab2[b][0:768)=pooled_micro [768:1536)=micro row0
//   blocks [2B,2B+CVT_BLOCKS): W1/W2 fp32 -> bf16 streaming convert (same layout)
// All stores fully coalesced.
// ---------------------------------------------------------------------------
__global__ __launch_bounds__(192) void pool_cvt_kernel(
    const float* __restrict__ phys, const float* __restrict__ proc,
    const float* __restrict__ micro, const int* __restrict__ pos,
    const float* __restrict__ W1, const float* __restrict__ W2,
    __hip_bfloat16* __restrict__ Ab1, __hip_bfloat16* __restrict__ Ab2,
    __hip_bfloat16* __restrict__ Wb1, __hip_bfloat16* __restrict__ Wb2) {
  const int t = threadIdx.x;  // 0..191
  const int NPOOL = 2 * B_;
  if (blockIdx.x < NPOOL) {
    const int b   = blockIdx.x >> 1;
    const int sel = blockIdx.x & 1;  // 0 = proc, 1 = micro
    __shared__ int sp[P_];
    __shared__ int scnt;
    if (t < 64) {  // wave 0 compacts valid positions
      int p = (t < P_) ? pos[b * P_ + t] : -1;
      bool valid = (p != -1);
      unsigned long long m = __ballot(valid);
      int pre = __popcll(m & ((1ull << t) - 1ull));
      if (valid) sp[pre] = p;
      if (t == 0) scnt = (int)__popcll(m);
    }
    __syncthreads();
    const int c = scnt;  // >= 1
    const float inv = 1.0f / (float)c;

    const int H4 = H_ / 4;  // 192
    const float* base = (sel == 0) ? proc : micro;
    const float4* srcb = (const float4*)(base + (size_t)b * S_ * H_);

    float4 sent = srcb[t];  // row 0 (issued early)
    float4 sph = make_float4(0.f, 0.f, 0.f, 0.f);
    if (sel == 0) sph = ((const float4*)(phys + (size_t)b * S_ * H_))[t];

    float4 s0 = make_float4(0.f, 0.f, 0.f, 0.f);
    float4 s1 = make_float4(0.f, 0.f, 0.f, 0.f);
    int i = 0;
    for (; i + 8 <= c; i += 8) {
      float4 v0 = srcb[(size_t)sp[i+0] * H4 + t];
      float4 v1 = srcb[(size_t)sp[i+1] * H4 + t];
      float4 v2 = srcb[(size_t)sp[i+2] * H4 + t];
      float4 v3 = srcb[(size_t)sp[i+3] * H4 + t];
      float4 v4 = srcb[(size_t)sp[i+4] * H4 + t];
      float4 v5 = srcb[(size_t)sp[i+5] * H4 + t];
      float4 v6 = srcb[(size_t)sp[i+6] * H4 + t];
      float4 v7 = srcb[(size_t)sp[i+7] * H4 + t];
      s0.x += v0.x + v1.x + v2.x + v3.x;  s1.x += v4.x + v5.x + v6.x + v7.x;
      s0.y += v0.y + v1.y + v2.y + v3.y;  s1.y += v4.y + v5.y + v6.y + v7.y;
      s0.z += v0.z + v1.z + v2.z + v3.z;  s1.z += v4.z + v5.z + v6.z + v7.z;
      s0.w += v0.w + v1.w + v2.w + v3.w;  s1.w += v4.w + v5.w + v6.w + v7.w;
    }
    for (; i + 2 <= c; i += 2) {
      float4 v0 = srcb[(size_t)sp[i+0] * H4 + t];
      float4 v1 = srcb[(size_t)sp[i+1] * H4 + t];
      s0.x += v0.x + v1.x; s0.y += v0.y + v1.y;
      s0.z += v0.z + v1.z; s0.w += v0.w + v1.w;
    }
    if (i < c) {
      float4 v = srcb[(size_t)sp[i] * H4 + t];
      s0.x += v.x; s0.y += v.y; s0.z += v.z; s0.w += v.w;
    }
    float4 pooled = make_float4((s0.x + s1.x) * inv, (s0.y + s1.y) * inv,
                                (s0.z + s1.z) * inv, (s0.w + s1.w) * inv);

    ushort4 up, us;
    up.x = bfb(pooled.x); up.y = bfb(pooled.y); up.z = bfb(pooled.z); up.w = bfb(pooled.w);
    us.x = bfb(sent.x);   us.y = bfb(sent.y);   us.z = bfb(sent.z);   us.w = bfb(sent.w);
    if (sel == 0) {
      __hip_bfloat16* row = Ab1 + (size_t)b * K1_;
      *reinterpret_cast<ushort4*>(row + t*4)          = up;
      *reinterpret_cast<ushort4*>(row + H_ + t*4)     = us;
      ushort4 uh;
      uh.x = bfb(sph.x); uh.y = bfb(sph.y); uh.z = bfb(sph.z); uh.w = bfb(sph.w);
      *reinterpret_cast<ushort4*>(row + 2*H_ + t*4)   = uh;
    } else {
      __hip_bfloat16* row = Ab2 + (size_t)b * K2_;
      *reinterpret_cast<ushort4*>(row + t*4)          = up;
      *reinterpret_cast<ushort4*>(row + H_ + t*4)     = us;
    }
  } else {
    // ---- W conversion: straight streaming fp32 -> bf16, 8 elems/thread ----
    const int G1 = (768 * K1_) / 8;  // 221184
    const int G2 = (768 * K2_) / 8;  // 147456
    int tid = (blockIdx.x - NPOOL) * 192 + t;
    const int stride = CVT_BLOCKS * 192;
    for (int g = tid; g < G1 + G2; g += stride) {
      const float* src; __hip_bfloat16* dst; int gg;
      if (g < G1) { src = W1; dst = Wb1; gg = g; }
      else        { src = W2; dst = Wb2; gg = g - G1; }
      const float4* s = (const float4*)(src + (size_t)gg * 8);
      float4 v0 = s[0], v1 = s[1];
      u16x8 o;
      o[0] = bfb(v0.x); o[1] = bfb(v0.y); o[2] = bfb(v0.z); o[3] = bfb(v0.w);
      o[4] = bfb(v1.x); o[5] = bfb(v1.y); o[6] = bfb(v1.z); o[7] = bfb(v1.w);
      *reinterpret_cast<u16x8*>(dst + (size_t)gg * 8) = o;
    }
  }
}

// ---------------------------------------------------------------------------
// Kernel 2: dual bf16 MFMA GEMM + bias. One wave per block, 64x64 tile
// (4x4 fragments, 16 MFMA/iter), direct strided loads from row-major bf16.
// XCD-swizzled: each XCD owns one (mt-half, nt-half) quadrant of one GEMM
// -> L2 working set ~2-3 MB < 4 MB/XCD.
// ---------------------------------------------------------------------------
template <int K>
__device__ inline void gemm_body(const __hip_bfloat16* __restrict__ Ab,
                                 const __hip_bfloat16* __restrict__ Wb,
                                 const float* __restrict__ bias,
                                 float* __restrict__ C, int mt, int nt) {
  const int lane = threadIdx.x;
  const int col16 = lane & 15;
  const int kg = lane >> 2 >> 2;   // lane>>4
  const int m0 = mt * 64, n0 = nt * 64;

  // per-lane base pointers: row (.. + col16), k-offset kg*8
  const __hip_bfloat16* pA = Ab + (size_t)(m0 + col16) * K + kg * 8;
  const __hip_bfloat16* pW = Wb + (size_t)(n0 + col16) * K + kg * 8;

  f32x4v acc[4][4];
#pragma unroll
  for (int a = 0; a < 4; ++a)
#pragma unroll
    for (int b = 0; b < 4; ++b) acc[a][b] = (f32x4v){0.f, 0.f, 0.f, 0.f};

#pragma unroll 2
  for (int k32 = 0; k32 < K / 32; ++k32) {
    bf16x8v af[4], wf[4];
#pragma unroll
    for (int i = 0; i < 4; ++i) {
      af[i] = *(const bf16x8v*)(pA + (size_t)i * 16 * K + k32 * 32);
      wf[i] = *(const bf16x8v*)(pW + (size_t)i * 16 * K + k32 * 32);
    }
#pragma unroll
    for (int a = 0; a < 4; ++a)
#pragma unroll
      for (int b = 0; b < 4; ++b)
        acc[a][b] = __builtin_amdgcn_mfma_f32_16x16x32_bf16(af[a], wf[b], acc[a][b], 0, 0, 0);
  }

  // C/D layout: col = lane&15, row = (lane>>4)*4 + j  (verified R2)
  const int rg = (lane >> 4) * 4;
  float bv[4];
#pragma unroll
  for (int b = 0; b < 4; ++b) bv[b] = bias[n0 + b * 16 + col16];
#pragma unroll
  for (int a = 0; a < 4; ++a)
#pragma unroll
    for (int j = 0; j < 4; ++j) {
      float* crow = C + (size_t)(m0 + a * 16 + rg + j) * N_ + n0 + col16;
#pragma unroll
      for (int b = 0; b < 4; ++b) crow[b * 16] = acc[a][b][j] + bv[b];
    }
}

__global__ __launch_bounds__(64) void gemm_kernel(
    const __hip_bfloat16* __restrict__ Ab1, const __hip_bfloat16* __restrict__ Ab2,
    const __hip_bfloat16* __restrict__ Wb1, const __hip_bfloat16* __restrict__ Wb2,
    const float* __restrict__ b1, const float* __restrict__ b2,
    float* __restrict__ out) {
  // 192 blocks. Assume round-robin blockIdx->XCD (blockIdx%8); each XCD gets
  // 24 slots = one quadrant (4 mt x 6 nt) of one GEMM.
  const int orig = blockIdx.x;
  const int xcd = orig & 7;
  const int slot = orig >> 3;       // 0..23
  const int g = xcd >> 2;           // 0: GEMM1, 1: GEMM2
  const int x = xcd & 3;
  const int mt = (x >> 1) * 4 + slot / 6;   // 0..7
  const int nt = (x & 1) * 6 + slot % 6;    // 0..11
  if (g == 0) {
    gemm_body<K1_>(Ab1, Wb1, b1, out, mt, nt);
  } else {
    gemm_body<K2_>(Ab2, Wb2, b2, out + (size_t)M_ * N_, mt, nt);
  }
}

// ---------------------------------------------------------------------------
// Kernel 3: in-place row L2 normalization of out (2*B rows of 768).
// ---------------------------------------------------------------------------
__global__ __launch_bounds__(256) void norm_rows_kernel(float* __restrict__ out) {
  const int row = blockIdx.x;  // 0..1023
  float* p = out + (size_t)row * N_;
  const int t = threadIdx.x;
  float x0 = p[t];
  float x1 = p[t + 256];
  float x2 = p[t + 512];
  float s = x0*x0 + x1*x1 + x2*x2;
#pragma unroll
  for (int off = 32; off > 0; off >>= 1) s += __shfl_down(s, off);
  __shared__ float ws[4];
  const int lane = t & 63, wid = t >> 6;
  if (lane == 0) ws[wid] = s;
  __syncthreads();
  float tot = ws[0] + ws[1] + ws[2] + ws[3];
  float inv = 1.0f / fmaxf(sqrtf(tot), 1e-12f);
  p[t]       = x0 * inv;
  p[t + 256] = x1 * inv;
  p[t + 512] = x2 * inv;
}

// ---------------------------------------------------------------------------
extern "C" void kernel_launch(void* const* d_in, const int* in_sizes, int n_in,
                              void* d_out, int out_size, void* d_ws, size_t ws_size,
                              hipStream_t stream) {
  const float* phys  = (const float*)d_in[0];
  const float* proc  = (const float*)d_in[1];
  const float* micro = (const float*)d_in[2];
  const int*   pos   = (const int*)d_in[3];
  const float* W1    = (const float*)d_in[4];
  const float* b1    = (const float*)d_in[5];
  const float* W2    = (const float*)d_in[6];
  const float* b2    = (const float*)d_in[7];
  float* out = (float*)d_out;

  // ws layout (bf16, all row-major): Ab1 | Ab2 | Wb1 | Wb2  (~9.8 MB)
  __hip_bfloat16* Ab1 = (__hip_bfloat16*)d_ws;
  __hip_bfloat16* Ab2 = Ab1 + (size_t)M_ * K1_;
  __hip_bfloat16* Wb1 = Ab2 + (size_t)M_ * K2_;
  __hip_bfloat16* Wb2 = Wb1 + (size_t)N_ * K1_;

  pool_cvt_kernel<<<2 * B_ + CVT_BLOCKS, 192, 0, stream>>>(
      phys, proc, micro, pos, W1, W2, Ab1, Ab2, Wb1, Wb2);
  gemm_kernel<<<192, 64, 0, stream>>>(Ab1, Ab2, Wb1, Wb2, b1, b2, out);
  norm_rows_kernel<<<2 * B_, 256, 0, stream>>>(out);
}

// Round 6
// 54.248 us; speedup vs baseline: 1.4192x; 1.4192x over previous
//
#include <hip/hip_runtime.h>
#include <hip/hip_bf16.h>

// Problem constants (B,S,H,P) = (512, 256, 768, 32)
#define B_  512
#define S_  256
#define H_  768
#define P_  32
#define K1_ 2304   // 3H
#define K2_ 1536   // 2H
#define N_  768
#define M_  512
#define CVT_BLOCKS 128

typedef __attribute__((ext_vector_type(8))) short bf16x8v;
typedef __attribute__((ext_vector_type(8))) unsigned short u16x8;
typedef __attribute__((ext_vector_type(4))) float f32x4v;

__device__ inline unsigned short bfb(float x) {
  __hip_bfloat16 h = __float2bfloat16(x);  // RNE
  return *reinterpret_cast<unsigned short*>(&h);
}

// W fragment layout (bf16), MFMA 16x16x32 B-operand order:
//   frag[n16][k32][lane][8], lane = kg*16 + r; element (n,k):
//   n = n16*16 + r, k = k32*32 + kg*8 + e.   (proven R2/R3)
// A stays ROW-MAJOR bf16; the GEMM loads the A-fragment directly:
//   addr = (m0 + i*16 + (lane&15))*K + k32*32 + (lane>>4)*8  (16x64B segments).

// ---------------------------------------------------------------------------
// Kernel 1 (fused):
//   blocks [0,2B): (batch,tensor) mean-pool + concat -> row-major bf16 A
//   blocks [2B,2B+CVT_BLOCKS): W1/W2 fp32 -> B-frag bf16 (coalesced stores)
// ---------------------------------------------------------------------------
__global__ __launch_bounds__(192) void pool_cvt_kernel(
    const float* __restrict__ phys, const float* __restrict__ proc,
    const float* __restrict__ micro, const int* __restrict__ pos,
    const float* __restrict__ W1, const float* __restrict__ W2,
    __hip_bfloat16* __restrict__ Ab1, __hip_bfloat16* __restrict__ Ab2,
    __hip_bfloat16* __restrict__ W1f, __hip_bfloat16* __restrict__ W2f) {
  const int t = threadIdx.x;  // 0..191
  const int NPOOL = 2 * B_;
  if (blockIdx.x < NPOOL) {
    const int b   = blockIdx.x >> 1;
    const int sel = blockIdx.x & 1;  // 0 = proc, 1 = micro
    __shared__ int sp[P_];
    __shared__ int scnt;
    if (t < 64) {  // wave 0 compacts valid positions
      int p = (t < P_) ? pos[b * P_ + t] : -1;
      bool valid = (p != -1);
      unsigned long long m = __ballot(valid);
      int pre = __popcll(m & ((1ull << t) - 1ull));
      if (valid) sp[pre] = p;
      if (t == 0) scnt = (int)__popcll(m);
    }
    __syncthreads();
    const int c = scnt;  // >= 1
    const float inv = 1.0f / (float)c;

    const int H4 = H_ / 4;  // 192
    const float* base = (sel == 0) ? proc : micro;
    const float4* srcb = (const float4*)(base + (size_t)b * S_ * H_);

    float4 sent = srcb[t];  // row 0 (issued early)
    float4 sph = make_float4(0.f, 0.f, 0.f, 0.f);
    if (sel == 0) sph = ((const float4*)(phys + (size_t)b * S_ * H_))[t];

    float4 s0 = make_float4(0.f, 0.f, 0.f, 0.f);
    float4 s1 = make_float4(0.f, 0.f, 0.f, 0.f);
    int i = 0;
    for (; i + 8 <= c; i += 8) {
      float4 v0 = srcb[(size_t)sp[i+0] * H4 + t];
      float4 v1 = srcb[(size_t)sp[i+1] * H4 + t];
      float4 v2 = srcb[(size_t)sp[i+2] * H4 + t];
      float4 v3 = srcb[(size_t)sp[i+3] * H4 + t];
      float4 v4 = srcb[(size_t)sp[i+4] * H4 + t];
      float4 v5 = srcb[(size_t)sp[i+5] * H4 + t];
      float4 v6 = srcb[(size_t)sp[i+6] * H4 + t];
      float4 v7 = srcb[(size_t)sp[i+7] * H4 + t];
      s0.x += v0.x + v1.x + v2.x + v3.x;  s1.x += v4.x + v5.x + v6.x + v7.x;
      s0.y += v0.y + v1.y + v2.y + v3.y;  s1.y += v4.y + v5.y + v6.y + v7.y;
      s0.z += v0.z + v1.z + v2.z + v3.z;  s1.z += v4.z + v5.z + v6.z + v7.z;
      s0.w += v0.w + v1.w + v2.w + v3.w;  s1.w += v4.w + v5.w + v6.w + v7.w;
    }
    for (; i + 2 <= c; i += 2) {
      float4 v0 = srcb[(size_t)sp[i+0] * H4 + t];
      float4 v1 = srcb[(size_t)sp[i+1] * H4 + t];
      s0.x += v0.x + v1.x; s0.y += v0.y + v1.y;
      s0.z += v0.z + v1.z; s0.w += v0.w + v1.w;
    }
    if (i < c) {
      float4 v = srcb[(size_t)sp[i] * H4 + t];
      s0.x += v.x; s0.y += v.y; s0.z += v.z; s0.w += v.w;
    }
    float4 pooled = make_float4((s0.x + s1.x) * inv, (s0.y + s1.y) * inv,
                                (s0.z + s1.z) * inv, (s0.w + s1.w) * inv);

    ushort4 up, us;
    up.x = bfb(pooled.x); up.y = bfb(pooled.y); up.z = bfb(pooled.z); up.w = bfb(pooled.w);
    us.x = bfb(sent.x);   us.y = bfb(sent.y);   us.z = bfb(sent.z);   us.w = bfb(sent.w);
    if (sel == 0) {
      __hip_bfloat16* row = Ab1 + (size_t)b * K1_;
      *reinterpret_cast<ushort4*>(row + t*4)          = up;
      *reinterpret_cast<ushort4*>(row + H_ + t*4)     = us;
      ushort4 uh;
      uh.x = bfb(sph.x); uh.y = bfb(sph.y); uh.z = bfb(sph.z); uh.w = bfb(sph.w);
      *reinterpret_cast<ushort4*>(row + 2*H_ + t*4)   = uh;
    } else {
      __hip_bfloat16* row = Ab2 + (size_t)b * K2_;
      *reinterpret_cast<ushort4*>(row + t*4)          = up;
      *reinterpret_cast<ushort4*>(row + H_ + t*4)     = us;
    }
  } else {
    // ---- W conversion into B-frag layout; consecutive g -> consecutive 16B
    const int NK1c = K1_ / 32, NK2c = K2_ / 32;
    const int NG1 = 48 * NK1c * 64;  // 221184 16B-groups
    const int NG2 = 48 * NK2c * 64;  // 147456
    int tid = (blockIdx.x - NPOOL) * 192 + t;
    const int stride = CVT_BLOCKS * 192;
    for (int g = tid; g < NG1 + NG2; g += stride) {
      const float* W; __hip_bfloat16* Wf; int NK, K, gg;
      if (g < NG1) { W = W1; Wf = W1f; NK = NK1c; K = K1_; gg = g; }
      else         { W = W2; Wf = W2f; NK = NK2c; K = K2_; gg = g - NG1; }
      int lane = gg & 63;
      int rest = gg >> 6;
      int k32 = rest % NK;
      int n16 = rest / NK;
      int n = n16 * 16 + (lane & 15);
      int k = k32 * 32 + (lane >> 4) * 8;
      const float4* sW = (const float4*)(W + (size_t)n * K + k);
      float4 v0 = sW[0], v1 = sW[1];
      u16x8 o;
      o[0] = bfb(v0.x); o[1] = bfb(v0.y); o[2] = bfb(v0.z); o[3] = bfb(v0.w);
      o[4] = bfb(v1.x); o[5] = bfb(v1.y); o[6] = bfb(v1.z); o[7] = bfb(v1.w);
      *reinterpret_cast<u16x8*>(Wf + (size_t)gg * 8) = o;
    }
  }
}

// ---------------------------------------------------------------------------
// Kernel 2: dual bf16 MFMA GEMM + bias. One wave per block, 64x64 tile,
// distance-2 register prefetch: loads for k-steps (k+2,k+3) are issued
// before the 32 MFMAs of (k,k+1), hiding L2 latency within the wave.
// A loaded from row-major (16x64B segments), W from frag layout (1KB cont.).
// ---------------------------------------------------------------------------
#define MFMA16(AV, WV)                                                        \
  _Pragma("unroll") for (int a = 0; a < 4; ++a)                               \
  _Pragma("unroll") for (int b = 0; b < 4; ++b)                               \
    acc[a][b] = __builtin_amdgcn_mfma_f32_16x16x32_bf16(AV[a], WV[b],         \
                                                        acc[a][b], 0, 0, 0);

template <int K>
__device__ inline void gemm_body(const __hip_bfloat16* __restrict__ Ab,
                                 const bf16x8v* __restrict__ Wf,
                                 const float* __restrict__ bias,
                                 float* __restrict__ C, int mt, int nt) {
  constexpr int NK = K / 32;
  const int lane = threadIdx.x;
  const int col16 = lane & 15;
  const int kg = lane >> 4;
  const int m0 = mt * 64, n0 = nt * 64;

  const __hip_bfloat16* pA = Ab + (size_t)(m0 + col16) * K + kg * 8;
  const bf16x8v* pW = Wf + (size_t)(4 * nt) * NK * 64 + lane;

  f32x4v acc[4][4];
#pragma unroll
  for (int a = 0; a < 4; ++a)
#pragma unroll
    for (int b = 0; b < 4; ++b) acc[a][b] = (f32x4v){0.f, 0.f, 0.f, 0.f};

  bf16x8v a0[4], w0[4], a1[4], w1[4];
#pragma unroll
  for (int i = 0; i < 4; ++i) {
    a0[i] = *(const bf16x8v*)(pA + (size_t)i * 16 * K);
    w0[i] = pW[(size_t)i * NK * 64];
    a1[i] = *(const bf16x8v*)(pA + (size_t)i * 16 * K + 32);
    w1[i] = pW[(size_t)i * NK * 64 + 64];
  }

  for (int k = 0; k < NK - 2; k += 2) {
    bf16x8v na[4], nw[4], nb[4], nx[4];
#pragma unroll
    for (int i = 0; i < 4; ++i) {
      na[i] = *(const bf16x8v*)(pA + (size_t)i * 16 * K + (size_t)(k + 2) * 32);
      nw[i] = pW[(size_t)i * NK * 64 + (size_t)(k + 2) * 64];
      nb[i] = *(const bf16x8v*)(pA + (size_t)i * 16 * K + (size_t)(k + 3) * 32);
      nx[i] = pW[(size_t)i * NK * 64 + (size_t)(k + 3) * 64];
    }
    MFMA16(a0, w0)
    MFMA16(a1, w1)
#pragma unroll
    for (int i = 0; i < 4; ++i) {
      a0[i] = na[i]; w0[i] = nw[i]; a1[i] = nb[i]; w1[i] = nx[i];
    }
  }
  MFMA16(a0, w0)
  MFMA16(a1, w1)

  // C/D layout: col = lane&15, row = (lane>>4)*4 + j  (verified R2)
  const int rg = (lane >> 4) * 4;
  float bv[4];
#pragma unroll
  for (int b = 0; b < 4; ++b) bv[b] = bias[n0 + b * 16 + col16];
#pragma unroll
  for (int a = 0; a < 4; ++a)
#pragma unroll
    for (int j = 0; j < 4; ++j) {
      float* crow = C + (size_t)(m0 + a * 16 + rg + j) * N_ + n0 + col16;
#pragma unroll
      for (int b = 0; b < 4; ++b) crow[b * 16] = acc[a][b][j] + bv[b];
    }
}

__global__ __launch_bounds__(64) void gemm_kernel(
    const __hip_bfloat16* __restrict__ Ab1, const __hip_bfloat16* __restrict__ Ab2,
    const __hip_bfloat16* __restrict__ W1f, const __hip_bfloat16* __restrict__ W2f,
    const float* __restrict__ b1, const float* __restrict__ b2,
    float* __restrict__ out) {
  // 192 blocks, parity-interleaved so both GEMMs spread across all XCDs.
  const int sel = blockIdx.x & 1;
  const int tl = blockIdx.x >> 1;   // 0..95
  const int mt = tl / 12;           // 0..7
  const int nt = tl % 12;           // 0..11
  if (sel == 0) {
    gemm_body<K1_>(Ab1, (const bf16x8v*)W1f, b1, out, mt, nt);
  } else {
    gemm_body<K2_>(Ab2, (const bf16x8v*)W2f, b2, out + (size_t)M_ * N_, mt, nt);
  }
}

// ---------------------------------------------------------------------------
// Kernel 3: in-place row L2 normalization of out (2*B rows of 768).
// ---------------------------------------------------------------------------
__global__ __launch_bounds__(256) void norm_rows_kernel(float* __restrict__ out) {
  const int row = blockIdx.x;  // 0..1023
  float* p = out + (size_t)row * N_;
  const int t = threadIdx.x;
  float x0 = p[t];
  float x1 = p[t + 256];
  float x2 = p[t + 512];
  float s = x0*x0 + x1*x1 + x2*x2;
#pragma unroll
  for (int off = 32; off > 0; off >>= 1) s += __shfl_down(s, off);
  __shared__ float ws[4];
  const int lane = t & 63, wid = t >> 6;
  if (lane == 0) ws[wid] = s;
  __syncthreads();
  float tot = ws[0] + ws[1] + ws[2] + ws[3];
  float inv = 1.0f / fmaxf(sqrtf(tot), 1e-12f);
  p[t]       = x0 * inv;
  p[t + 256] = x1 * inv;
  p[t + 512] = x2 * inv;
}

// ---------------------------------------------------------------------------
extern "C" void kernel_launch(void* const* d_in, const int* in_sizes, int n_in,
                              void* d_out, int out_size, void* d_ws, size_t ws_size,
                              hipStream_t stream) {
  const float* phys  = (const float*)d_in[0];
  const float* proc  = (const float*)d_in[1];
  const float* micro = (const float*)d_in[2];
  const int*   pos   = (const int*)d_in[3];
  const float* W1    = (const float*)d_in[4];
  const float* b1    = (const float*)d_in[5];
  const float* W2    = (const float*)d_in[6];
  const float* b2    = (const float*)d_in[7];
  float* out = (float*)d_out;

  // ws layout (bf16): Ab1 (row-major) | Ab2 (row-major) | W1f (frag) | W2f (frag)
  __hip_bfloat16* Ab1 = (__hip_bfloat16*)d_ws;
  __hip_bfloat16* Ab2 = Ab1 + (size_t)M_ * K1_;
  __hip_bfloat16* W1f = Ab2 + (size_t)M_ * K2_;
  __hip_bfloat16* W2f = W1f + (size_t)N_ * K1_;

  pool_cvt_kernel<<<2 * B_ + CVT_BLOCKS, 192, 0, stream>>>(
      phys, proc, micro, pos, W1, W2, Ab1, Ab2, W1f, W2f);
  gemm_kernel<<<192, 64, 0, stream>>>(Ab1, Ab2, W1f, W2f, b1, b2, out);
  norm_rows_kernel<<<2 * B_, 256, 0, stream>>>(out);
}

// Round 7
// 48.182 us; speedup vs baseline: 1.5979x; 1.1259x over previous
//
#include <hip/hip_runtime.h>
#include <hip/hip_bf16.h>

// Problem constants (B,S,H,P) = (512, 256, 768, 32)
#define B_  512
#define S_  256
#define H_  768
#define P_  32
#define K1_ 2304   // 3H
#define K2_ 1536   // 2H
#define N_  768
#define M_  512
#define NK1 72     // K1/32
#define NK2 48     // K2/32
#define CVT_BLOCKS 128

typedef __attribute__((ext_vector_type(8))) short bf16x8v;
typedef __attribute__((ext_vector_type(8))) unsigned short u16x8;
typedef __attribute__((ext_vector_type(4))) float f32x4v;

__device__ inline unsigned short bfb(float x) {
  __hip_bfloat16 h = __float2bfloat16(x);  // RNE
  return *reinterpret_cast<unsigned short*>(&h);
}

// Fragment layout (bf16), MFMA 16x16x32 operand order (proven R2/R3):
//   frag[t16][k32][lane][8], lane = kg*16 + r; element (t,k):
//   t = t16*16 + r, k = k32*32 + kg*8 + e.

// store 4 consecutive-k bf16 values (k % 4 == 0) into frag layout, 8B store
__device__ inline void store4_frag(__hip_bfloat16* __restrict__ buf, int NK,
                                   int m, int k, float4 v) {
  int m16 = m >> 4, mr = m & 15, k32 = k >> 5, kg = (k >> 3) & 3, e = k & 7;
  size_t off = ((size_t)(m16 * NK + k32) * 64 + kg * 16 + mr) * 8 + e;
  ushort4 u;
  u.x = bfb(v.x); u.y = bfb(v.y); u.z = bfb(v.z); u.w = bfb(v.w);
  *reinterpret_cast<ushort4*>(buf + off) = u;
}

// ---------------------------------------------------------------------------
// Kernel 1 (fused): blocks [0,2B): (batch,tensor) mean-pool -> A-frag bf16.
//   Block swizzle: the 4 blocks whose 16B stores share each 64B A-frag line
//   (batches 4j..4j+3, same tensor) are placed at blockIdx with equal value
//   mod 8 -> same XCD (round-robin dispatch) -> partial writes merge in L2.
// blocks [2B, 2B+CVT_BLOCKS): W1/W2 fp32 -> B-frag bf16 (grid-stride).
// ---------------------------------------------------------------------------
__global__ __launch_bounds__(192) void pool_cvt_kernel(
    const float* __restrict__ phys, const float* __restrict__ proc,
    const float* __restrict__ micro, const int* __restrict__ pos,
    const float* __restrict__ W1, const float* __restrict__ W2,
    __hip_bfloat16* __restrict__ A1f, __hip_bfloat16* __restrict__ A2f,
    __hip_bfloat16* __restrict__ W1f, __hip_bfloat16* __restrict__ W2f) {
  const int t = threadIdx.x;  // 0..191
  const int NPOOL = 2 * B_;   // 1024
  if (blockIdx.x < NPOOL) {
    // decode swizzle: bid = x + 8*(e + 4*sghi), sg = sghi*8 + x
    const int bid = blockIdx.x;
    const int x = bid & 7;
    const int r2 = bid >> 3;
    const int e = r2 & 3;
    const int sghi = r2 >> 2;          // 0..31
    const int sg = sghi * 8 + x;       // 0..255
    const int rsub = sg & 3;
    const int selm = sg >> 2;          // 0..63
    const int sel = selm >> 5;         // 0: proc, 1: micro
    const int m16 = selm & 31;
    const int b = m16 * 16 + rsub * 4 + e;

    __shared__ int sp[P_];
    __shared__ int scnt;
    if (t < 64) {  // wave 0 compacts valid positions
      int p = (t < P_) ? pos[b * P_ + t] : -1;
      bool valid = (p != -1);
      unsigned long long m = __ballot(valid);
      int pre = __popcll(m & ((1ull << t) - 1ull));
      if (valid) sp[pre] = p;
      if (t == 0) scnt = (int)__popcll(m);
    }
    __syncthreads();
    const int c = scnt;  // >= 1
    const float inv = 1.0f / (float)c;

    const int H4 = H_ / 4;  // 192
    const float* base = (sel == 0) ? proc : micro;
    const float4* srcb = (const float4*)(base + (size_t)b * S_ * H_);

    float4 sent = srcb[t];  // row 0 (issued early)
    float4 sph = make_float4(0.f, 0.f, 0.f, 0.f);
    if (sel == 0) sph = ((const float4*)(phys + (size_t)b * S_ * H_))[t];

    float4 s0 = make_float4(0.f, 0.f, 0.f, 0.f);
    float4 s1 = make_float4(0.f, 0.f, 0.f, 0.f);
    int i = 0;
    for (; i + 8 <= c; i += 8) {
      float4 v0 = srcb[(size_t)sp[i+0] * H4 + t];
      float4 v1 = srcb[(size_t)sp[i+1] * H4 + t];
      float4 v2 = srcb[(size_t)sp[i+2] * H4 + t];
      float4 v3 = srcb[(size_t)sp[i+3] * H4 + t];
      float4 v4 = srcb[(size_t)sp[i+4] * H4 + t];
      float4 v5 = srcb[(size_t)sp[i+5] * H4 + t];
      float4 v6 = srcb[(size_t)sp[i+6] * H4 + t];
      float4 v7 = srcb[(size_t)sp[i+7] * H4 + t];
      s0.x += v0.x + v1.x + v2.x + v3.x;  s1.x += v4.x + v5.x + v6.x + v7.x;
      s0.y += v0.y + v1.y + v2.y + v3.y;  s1.y += v4.y + v5.y + v6.y + v7.y;
      s0.z += v0.z + v1.z + v2.z + v3.z;  s1.z += v4.z + v5.z + v6.z + v7.z;
      s0.w += v0.w + v1.w + v2.w + v3.w;  s1.w += v4.w + v5.w + v6.w + v7.w;
    }
    for (; i + 2 <= c; i += 2) {
      float4 v0 = srcb[(size_t)sp[i+0] * H4 + t];
      float4 v1 = srcb[(size_t)sp[i+1] * H4 + t];
      s0.x += v0.x + v1.x; s0.y += v0.y + v1.y;
      s0.z += v0.z + v1.z; s0.w += v0.w + v1.w;
    }
    if (i < c) {
      float4 v = srcb[(size_t)sp[i] * H4 + t];
      s0.x += v.x; s0.y += v.y; s0.z += v.z; s0.w += v.w;
    }
    float4 pooled = make_float4((s0.x + s1.x) * inv, (s0.y + s1.y) * inv,
                                (s0.z + s1.z) * inv, (s0.w + s1.w) * inv);

    const int k = t * 4;
    if (sel == 0) {
      store4_frag(A1f, NK1, b, k,          pooled);
      store4_frag(A1f, NK1, b, k + H_,     sent);
      store4_frag(A1f, NK1, b, k + 2*H_,   sph);
    } else {
      store4_frag(A2f, NK2, b, k,          pooled);
      store4_frag(A2f, NK2, b, k + H_,     sent);
    }
  } else {
    // ---- W conversion into B-frag layout; consecutive g -> consecutive 16B
    const int NG1 = 48 * NK1 * 64;  // 221184
    const int NG2 = 48 * NK2 * 64;  // 147456
    int tid = (blockIdx.x - NPOOL) * 192 + t;
    const int stride = CVT_BLOCKS * 192;
    for (int g = tid; g < NG1 + NG2; g += stride) {
      const float* W; __hip_bfloat16* Wf; int NK, K, gg;
      if (g < NG1) { W = W1; Wf = W1f; NK = NK1; K = K1_; gg = g; }
      else         { W = W2; Wf = W2f; NK = NK2; K = K2_; gg = g - NG1; }
      int lane = gg & 63;
      int rest = gg >> 6;
      int k32 = rest % NK;
      int n16 = rest / NK;
      int n = n16 * 16 + (lane & 15);
      int k = k32 * 32 + (lane >> 4) * 8;
      const float4* sW = (const float4*)(W + (size_t)n * K + k);
      float4 v0 = sW[0], v1 = sW[1];
      u16x8 o;
      o[0] = bfb(v0.x); o[1] = bfb(v0.y); o[2] = bfb(v0.z); o[3] = bfb(v0.w);
      o[4] = bfb(v1.x); o[5] = bfb(v1.y); o[6] = bfb(v1.z); o[7] = bfb(v1.w);
      *reinterpret_cast<u16x8*>(Wf + (size_t)gg * 8) = o;
    }
  }
}

// ---------------------------------------------------------------------------
// Kernel 2: dual bf16 MFMA GEMM (R3 structure: one wave per block, 32x32
// tile, both operands frag-layout, fully-coalesced 1KB loads) + distance-2
// register prefetch (R6-proven) + XCD n-column swizzle (W/A L2 residency).
// ---------------------------------------------------------------------------
#define MFMA4(A0V, A1V, W0V, W1V)                                             \
  acc00 = __builtin_amdgcn_mfma_f32_16x16x32_bf16(A0V, W0V, acc00, 0, 0, 0);  \
  acc01 = __builtin_amdgcn_mfma_f32_16x16x32_bf16(A0V, W1V, acc01, 0, 0, 0);  \
  acc10 = __builtin_amdgcn_mfma_f32_16x16x32_bf16(A1V, W0V, acc10, 0, 0, 0);  \
  acc11 = __builtin_amdgcn_mfma_f32_16x16x32_bf16(A1V, W1V, acc11, 0, 0, 0);

template <int NK>
__device__ inline void gemm_body(const bf16x8v* __restrict__ Af,
                                 const bf16x8v* __restrict__ Wf,
                                 const float* __restrict__ bias,
                                 float* __restrict__ C, int mt, int nt) {
  const int lane = threadIdx.x;

  const bf16x8v* A0 = Af + (size_t)(2 * mt) * NK * 64 + lane;
  const bf16x8v* A1 = A0 + (size_t)NK * 64;
  const bf16x8v* B0 = Wf + (size_t)(2 * nt) * NK * 64 + lane;
  const bf16x8v* B1 = B0 + (size_t)NK * 64;

  f32x4v acc00 = {0.f, 0.f, 0.f, 0.f};
  f32x4v acc01 = {0.f, 0.f, 0.f, 0.f};
  f32x4v acc10 = {0.f, 0.f, 0.f, 0.f};
  f32x4v acc11 = {0.f, 0.f, 0.f, 0.f};

  // steady state: hold steps k,k+1 in regs, prefetch k+2,k+3 before MFMAs
  bf16x8v a0s0 = A0[0],  a1s0 = A1[0],  w0s0 = B0[0],  w1s0 = B1[0];
  bf16x8v a0s1 = A0[64], a1s1 = A1[64], w0s1 = B0[64], w1s1 = B1[64];

  for (int k = 0; k < NK - 2; k += 2) {
    bf16x8v pa0 = A0[(size_t)(k + 2) * 64];
    bf16x8v pa1 = A1[(size_t)(k + 2) * 64];
    bf16x8v pw0 = B0[(size_t)(k + 2) * 64];
    bf16x8v pw1 = B1[(size_t)(k + 2) * 64];
    bf16x8v qa0 = A0[(size_t)(k + 3) * 64];
    bf16x8v qa1 = A1[(size_t)(k + 3) * 64];
    bf16x8v qw0 = B0[(size_t)(k + 3) * 64];
    bf16x8v qw1 = B1[(size_t)(k + 3) * 64];
    MFMA4(a0s0, a1s0, w0s0, w1s0)
    MFMA4(a0s1, a1s1, w0s1, w1s1)
    a0s0 = pa0; a1s0 = pa1; w0s0 = pw0; w1s0 = pw1;
    a0s1 = qa0; a1s1 = qa1; w0s1 = qw0; w1s1 = qw1;
  }
  MFMA4(a0s0, a1s0, w0s0, w1s0)
  MFMA4(a0s1, a1s1, w0s1, w1s1)

  // C/D layout: col = lane&15, row = (lane>>4)*4 + j  (verified R2)
  const int m0 = mt * 32, n0 = nt * 32;
  const int col = lane & 15;
  const int rg = (lane >> 4) * 4;
  const float bv0 = bias[n0 + col];
  const float bv1 = bias[n0 + 16 + col];
#pragma unroll
  for (int j = 0; j < 4; ++j) {
    const int r = rg + j;
    C[(size_t)(m0 + r) * N_ + n0 + col]           = acc00[j] + bv0;
    C[(size_t)(m0 + r) * N_ + n0 + 16 + col]      = acc01[j] + bv1;
    C[(size_t)(m0 + 16 + r) * N_ + n0 + col]      = acc10[j] + bv0;
    C[(size_t)(m0 + 16 + r) * N_ + n0 + 16 + col] = acc11[j] + bv1;
  }
}

__global__ __launch_bounds__(64) void gemm_mfma_kernel(
    const __hip_bfloat16* __restrict__ A1f, const __hip_bfloat16* __restrict__ A2f,
    const __hip_bfloat16* __restrict__ W1f, const __hip_bfloat16* __restrict__ W2f,
    const float* __restrict__ b1, const float* __restrict__ b2,
    float* __restrict__ out) {
  // 768 blocks. XCD x owns global n-columns ntp = 6x..6x+5 (48 total over
  // both GEMMs): W + A working set per XCD ~3.3 MB < 4 MB L2.
  const int bid = blockIdx.x;
  const int x = bid & 7;
  const int local = bid >> 3;        // 0..95
  const int mt = local / 6;          // 0..15
  const int ntp = x * 6 + local % 6; // 0..47
  if (ntp < 24) {
    gemm_body<NK1>((const bf16x8v*)A1f, (const bf16x8v*)W1f, b1, out, mt, ntp);
  } else {
    gemm_body<NK2>((const bf16x8v*)A2f, (const bf16x8v*)W2f, b2,
                   out + (size_t)M_ * N_, mt, ntp - 24);
  }
}

// ---------------------------------------------------------------------------
// Kernel 3: in-place row L2 normalization of out (2*B rows of 768).
// ---------------------------------------------------------------------------
__global__ __launch_bounds__(256) void norm_rows_kernel(float* __restrict__ out) {
  const int row = blockIdx.x;  // 0..1023
  float* p = out + (size_t)row * N_;
  const int t = threadIdx.x;
  float x0 = p[t];
  float x1 = p[t + 256];
  float x2 = p[t + 512];
  float s = x0*x0 + x1*x1 + x2*x2;
#pragma unroll
  for (int off = 32; off > 0; off >>= 1) s += __shfl_down(s, off);
  __shared__ float ws[4];
  const int lane = t & 63, wid = t >> 6;
  if (lane == 0) ws[wid] = s;
  __syncthreads();
  float tot = ws[0] + ws[1] + ws[2] + ws[3];
  float inv = 1.0f / fmaxf(sqrtf(tot), 1e-12f);
  p[t]       = x0 * inv;
  p[t + 256] = x1 * inv;
  p[t + 512] = x2 * inv;
}

// ---------------------------------------------------------------------------
extern "C" void kernel_launch(void* const* d_in, const int* in_sizes, int n_in,
                              void* d_out, int out_size, void* d_ws, size_t ws_size,
                              hipStream_t stream) {
  const float* phys  = (const float*)d_in[0];
  const float* proc  = (const float*)d_in[1];
  const float* micro = (const float*)d_in[2];
  const int*   pos   = (const int*)d_in[3];
  const float* W1    = (const float*)d_in[4];
  const float* b1    = (const float*)d_in[5];
  const float* W2    = (const float*)d_in[6];
  const float* b2    = (const float*)d_in[7];
  float* out = (float*)d_out;

  // ws layout (bf16): A1f | A2f | W1f | W2f  (~9.4 MB)
  __hip_bfloat16* A1f = (__hip_bfloat16*)d_ws;
  __hip_bfloat16* A2f = A1f + (size_t)32 * NK1 * 512;
  __hip_bfloat16* W1f = A2f + (size_t)32 * NK2 * 512;
  __hip_bfloat16* W2f = W1f + (size_t)48 * NK1 * 512;

  pool_cvt_kernel<<<2 * B_ + CVT_BLOCKS, 192, 0, stream>>>(
      phys, proc, micro, pos, W1, W2, A1f, A2f, W1f, W2f);
  gemm_mfma_kernel<<<2 * (M_ / 32) * (N_ / 32), 64, 0, stream>>>(
      A1f, A2f, W1f, W2f, b1, b2, out);
  norm_rows_kernel<<<2 * B_, 256, 0, stream>>>(out);
}

// Round 8
// 45.412 us; speedup vs baseline: 1.6954x; 1.0610x over previous
//
#include <hip/hip_runtime.h>
#include <hip/hip_bf16.h>

// Problem constants (B,S,H,P) = (512, 256, 768, 32)
#define B_  512
#define S_  256
#define H_  768
#define P_  32
#define K1_ 2304   // 3H
#define K2_ 1536   // 2H
#define N_  768
#define M_  512
#define NK1 72     // K1/32
#define NK2 48     // K2/32
#define CVT_BLOCKS 512

typedef __attribute__((ext_vector_type(8))) short bf16x8v;
typedef __attribute__((ext_vector_type(8))) unsigned short u16x8;
typedef __attribute__((ext_vector_type(4))) float f32x4v;

__device__ inline unsigned short bfb(float x) {
  __hip_bfloat16 h = __float2bfloat16(x);  // RNE
  return *reinterpret_cast<unsigned short*>(&h);
}

// Fragment layout (bf16), MFMA 16x16x32 operand order (proven R2/R3):
//   frag[t16][k32][lane][8], lane = kg*16 + r; element (t,k):
//   t = t16*16 + r, k = k32*32 + kg*8 + e.

// store 4 consecutive-k bf16 values (k % 4 == 0) into frag layout, 8B store
__device__ inline void store4_frag(__hip_bfloat16* __restrict__ buf, int NK,
                                   int m, int k, float4 v) {
  int m16 = m >> 4, mr = m & 15, k32 = k >> 5, kg = (k >> 3) & 3, e = k & 7;
  size_t off = ((size_t)(m16 * NK + k32) * 64 + kg * 16 + mr) * 8 + e;
  ushort4 u;
  u.x = bfb(v.x); u.y = bfb(v.y); u.z = bfb(v.z); u.w = bfb(v.w);
  *reinterpret_cast<ushort4*>(buf + off) = u;
}

// ---------------------------------------------------------------------------
// Kernel 1 (fused): blocks [0,2B): (batch,tensor) mean-pool -> A-frag bf16.
// blocks [2B, 2B+CVT_BLOCKS): W1/W2 fp32 -> B-frag bf16 (grid-stride).
// ---------------------------------------------------------------------------
__global__ __launch_bounds__(192) void pool_cvt_kernel(
    const float* __restrict__ phys, const float* __restrict__ proc,
    const float* __restrict__ micro, const int* __restrict__ pos,
    const float* __restrict__ W1, const float* __restrict__ W2,
    __hip_bfloat16* __restrict__ A1f, __hip_bfloat16* __restrict__ A2f,
    __hip_bfloat16* __restrict__ W1f, __hip_bfloat16* __restrict__ W2f) {
  const int t = threadIdx.x;  // 0..191
  const int NPOOL = 2 * B_;   // 1024
  if (blockIdx.x < NPOOL) {
    // swizzle (R7): 4 blocks sharing each 64B A-frag line land on one XCD
    const int bid = blockIdx.x;
    const int x = bid & 7;
    const int r2 = bid >> 3;
    const int e = r2 & 3;
    const int sghi = r2 >> 2;          // 0..31
    const int sg = sghi * 8 + x;       // 0..255
    const int rsub = sg & 3;
    const int selm = sg >> 2;          // 0..63
    const int sel = selm >> 5;         // 0: proc, 1: micro
    const int m16 = selm & 31;
    const int b = m16 * 16 + rsub * 4 + e;

    __shared__ int sp[P_];
    __shared__ int scnt;
    if (t < 64) {  // wave 0 compacts valid positions
      int p = (t < P_) ? pos[b * P_ + t] : -1;
      bool valid = (p != -1);
      unsigned long long m = __ballot(valid);
      int pre = __popcll(m & ((1ull << t) - 1ull));
      if (valid) sp[pre] = p;
      if (t == 0) scnt = (int)__popcll(m);
    }
    __syncthreads();
    const int c = scnt;  // >= 1
    const float inv = 1.0f / (float)c;

    const int H4 = H_ / 4;  // 192
    const float* base = (sel == 0) ? proc : micro;
    const float4* srcb = (const float4*)(base + (size_t)b * S_ * H_);

    float4 sent = srcb[t];  // row 0 (issued early)
    float4 sph = make_float4(0.f, 0.f, 0.f, 0.f);
    if (sel == 0) sph = ((const float4*)(phys + (size_t)b * S_ * H_))[t];

    float4 s0 = make_float4(0.f, 0.f, 0.f, 0.f);
    float4 s1 = make_float4(0.f, 0.f, 0.f, 0.f);
    int i = 0;
    for (; i + 8 <= c; i += 8) {
      float4 v0 = srcb[(size_t)sp[i+0] * H4 + t];
      float4 v1 = srcb[(size_t)sp[i+1] * H4 + t];
      float4 v2 = srcb[(size_t)sp[i+2] * H4 + t];
      float4 v3 = srcb[(size_t)sp[i+3] * H4 + t];
      float4 v4 = srcb[(size_t)sp[i+4] * H4 + t];
      float4 v5 = srcb[(size_t)sp[i+5] * H4 + t];
      float4 v6 = srcb[(size_t)sp[i+6] * H4 + t];
      float4 v7 = srcb[(size_t)sp[i+7] * H4 + t];
      s0.x += v0.x + v1.x + v2.x + v3.x;  s1.x += v4.x + v5.x + v6.x + v7.x;
      s0.y += v0.y + v1.y + v2.y + v3.y;  s1.y += v4.y + v5.y + v6.y + v7.y;
      s0.z += v0.z + v1.z + v2.z + v3.z;  s1.z += v4.z + v5.z + v6.z + v7.z;
      s0.w += v0.w + v1.w + v2.w + v3.w;  s1.w += v4.w + v5.w + v6.w + v7.w;
    }
    for (; i + 2 <= c; i += 2) {
      float4 v0 = srcb[(size_t)sp[i+0] * H4 + t];
      float4 v1 = srcb[(size_t)sp[i+1] * H4 + t];
      s0.x += v0.x + v1.x; s0.y += v0.y + v1.y;
      s0.z += v0.z + v1.z; s0.w += v0.w + v1.w;
    }
    if (i < c) {
      float4 v = srcb[(size_t)sp[i] * H4 + t];
      s0.x += v.x; s0.y += v.y; s0.z += v.z; s0.w += v.w;
    }
    float4 pooled = make_float4((s0.x + s1.x) * inv, (s0.y + s1.y) * inv,
                                (s0.z + s1.z) * inv, (s0.w + s1.w) * inv);

    const int k = t * 4;
    if (sel == 0) {
      store4_frag(A1f, NK1, b, k,          pooled);
      store4_frag(A1f, NK1, b, k + H_,     sent);
      store4_frag(A1f, NK1, b, k + 2*H_,   sph);
    } else {
      store4_frag(A2f, NK2, b, k,          pooled);
      store4_frag(A2f, NK2, b, k + H_,     sent);
    }
  } else {
    // ---- W conversion into B-frag layout; consecutive g -> consecutive 16B
    const int NG1 = 48 * NK1 * 64;  // 221184
    const int NG2 = 48 * NK2 * 64;  // 147456
    int tid = (blockIdx.x - NPOOL) * 192 + t;
    const int stride = CVT_BLOCKS * 192;
    for (int g = tid; g < NG1 + NG2; g += stride) {
      const float* W; __hip_bfloat16* Wf; int NK, K, gg;
      if (g < NG1) { W = W1; Wf = W1f; NK = NK1; K = K1_; gg = g; }
      else         { W = W2; Wf = W2f; NK = NK2; K = K2_; gg = g - NG1; }
      int lane = gg & 63;
      int rest = gg >> 6;
      int k32 = rest % NK;
      int n16 = rest / NK;
      int n = n16 * 16 + (lane & 15);
      int k = k32 * 32 + (lane >> 4) * 8;
      const float4* sW = (const float4*)(W + (size_t)n * K + k);
      float4 v0 = sW[0], v1 = sW[1];
      u16x8 o;
      o[0] = bfb(v0.x); o[1] = bfb(v0.y); o[2] = bfb(v0.z); o[3] = bfb(v0.w);
      o[4] = bfb(v1.x); o[5] = bfb(v1.y); o[6] = bfb(v1.z); o[7] = bfb(v1.w);
      *reinterpret_cast<u16x8*>(Wf + (size_t)gg * 8) = o;
    }
  }
}

// ---------------------------------------------------------------------------
// Kernel 2: dual bf16 MFMA GEMM. 4-wave blocks, 64x64 block tile = 2x2 waves
// of 32x32 (proven R3 inner loop + d2 prefetch). Waves pairwise share
// A-frags / W-frags -> L1 catches duplicate loads, L2 traffic halves.
// XCD swizzle: XCD x owns 3 of 24 block-columns -> ~3.4 MB < 4 MB L2.
// ---------------------------------------------------------------------------
#define MFMA4(A0V, A1V, W0V, W1V)                                             \
  acc00 = __builtin_amdgcn_mfma_f32_16x16x32_bf16(A0V, W0V, acc00, 0, 0, 0);  \
  acc01 = __builtin_amdgcn_mfma_f32_16x16x32_bf16(A0V, W1V, acc01, 0, 0, 0);  \
  acc10 = __builtin_amdgcn_mfma_f32_16x16x32_bf16(A1V, W0V, acc10, 0, 0, 0);  \
  acc11 = __builtin_amdgcn_mfma_f32_16x16x32_bf16(A1V, W1V, acc11, 0, 0, 0);

template <int NK>
__device__ inline void gemm_body(const bf16x8v* __restrict__ Af,
                                 const bf16x8v* __restrict__ Wf,
                                 const float* __restrict__ bias,
                                 float* __restrict__ C, int mt, int nt) {
  const int lane = threadIdx.x & 63;

  const bf16x8v* A0 = Af + (size_t)(2 * mt) * NK * 64 + lane;
  const bf16x8v* A1 = A0 + (size_t)NK * 64;
  const bf16x8v* B0 = Wf + (size_t)(2 * nt) * NK * 64 + lane;
  const bf16x8v* B1 = B0 + (size_t)NK * 64;

  f32x4v acc00 = {0.f, 0.f, 0.f, 0.f};
  f32x4v acc01 = {0.f, 0.f, 0.f, 0.f};
  f32x4v acc10 = {0.f, 0.f, 0.f, 0.f};
  f32x4v acc11 = {0.f, 0.f, 0.f, 0.f};

  // steady state: hold steps k,k+1 in regs, prefetch k+2,k+3 before MFMAs
  bf16x8v a0s0 = A0[0],  a1s0 = A1[0],  w0s0 = B0[0],  w1s0 = B1[0];
  bf16x8v a0s1 = A0[64], a1s1 = A1[64], w0s1 = B0[64], w1s1 = B1[64];

  for (int k = 0; k < NK - 2; k += 2) {
    bf16x8v pa0 = A0[(size_t)(k + 2) * 64];
    bf16x8v pa1 = A1[(size_t)(k + 2) * 64];
    bf16x8v pw0 = B0[(size_t)(k + 2) * 64];
    bf16x8v pw1 = B1[(size_t)(k + 2) * 64];
    bf16x8v qa0 = A0[(size_t)(k + 3) * 64];
    bf16x8v qa1 = A1[(size_t)(k + 3) * 64];
    bf16x8v qw0 = B0[(size_t)(k + 3) * 64];
    bf16x8v qw1 = B1[(size_t)(k + 3) * 64];
    MFMA4(a0s0, a1s0, w0s0, w1s0)
    MFMA4(a0s1, a1s1, w0s1, w1s1)
    a0s0 = pa0; a1s0 = pa1; w0s0 = pw0; w1s0 = pw1;
    a0s1 = qa0; a1s1 = qa1; w0s1 = qw0; w1s1 = qw1;
  }
  MFMA4(a0s0, a1s0, w0s0, w1s0)
  MFMA4(a0s1, a1s1, w0s1, w1s1)

  // C/D layout: col = lane&15, row = (lane>>4)*4 + j  (verified R2)
  const int m0 = mt * 32, n0 = nt * 32;
  const int col = lane & 15;
  const int rg = (lane >> 4) * 4;
  const float bv0 = bias[n0 + col];
  const float bv1 = bias[n0 + 16 + col];
#pragma unroll
  for (int j = 0; j < 4; ++j) {
    const int r = rg + j;
    C[(size_t)(m0 + r) * N_ + n0 + col]           = acc00[j] + bv0;
    C[(size_t)(m0 + r) * N_ + n0 + 16 + col]      = acc01[j] + bv1;
    C[(size_t)(m0 + 16 + r) * N_ + n0 + col]      = acc10[j] + bv0;
    C[(size_t)(m0 + 16 + r) * N_ + n0 + 16 + col] = acc11[j] + bv1;
  }
}

__global__ __launch_bounds__(256) void gemm_mfma_kernel(
    const __hip_bfloat16* __restrict__ A1f, const __hip_bfloat16* __restrict__ A2f,
    const __hip_bfloat16* __restrict__ W1f, const __hip_bfloat16* __restrict__ W2f,
    const float* __restrict__ b1, const float* __restrict__ b2,
    float* __restrict__ out) {
  // 192 blocks x 256 thr. Block tile 64x64 = 2x2 waves of 32x32.
  // XCD x (bid&7) owns 3 consecutive of the 24 block-columns (2 GEMMs x 12).
  const int bid = blockIdx.x;
  const int x = bid & 7;
  const int local = bid >> 3;           // 0..23
  const int ntb_g = x * 3 + local % 3;  // 0..23 global block-column
  const int mtb = local / 3;            // 0..7
  const int wid = threadIdx.x >> 6;     // 0..3
  const int wr = wid >> 1, wc = wid & 1;
  const int mt = mtb * 2 + wr;          // 0..15 (32-row tile)
  if (ntb_g < 12) {
    const int nt = ntb_g * 2 + wc;      // 0..23
    gemm_body<NK1>((const bf16x8v*)A1f, (const bf16x8v*)W1f, b1, out, mt, nt);
  } else {
    const int nt = (ntb_g - 12) * 2 + wc;
    gemm_body<NK2>((const bf16x8v*)A2f, (const bf16x8v*)W2f, b2,
                   out + (size_t)M_ * N_, mt, nt);
  }
}

// ---------------------------------------------------------------------------
// Kernel 3: in-place row L2 normalization of out (2*B rows of 768).
// ---------------------------------------------------------------------------
__global__ __launch_bounds__(256) void norm_rows_kernel(float* __restrict__ out) {
  const int row = blockIdx.x;  // 0..1023
  float* p = out + (size_t)row * N_;
  const int t = threadIdx.x;
  float x0 = p[t];
  float x1 = p[t + 256];
  float x2 = p[t + 512];
  float s = x0*x0 + x1*x1 + x2*x2;
#pragma unroll
  for (int off = 32; off > 0; off >>= 1) s += __shfl_down(s, off);
  __shared__ float ws[4];
  const int lane = t & 63, wid = t >> 6;
  if (lane == 0) ws[wid] = s;
  __syncthreads();
  float tot = ws[0] + ws[1] + ws[2] + ws[3];
  float inv = 1.0f / fmaxf(sqrtf(tot), 1e-12f);
  p[t]       = x0 * inv;
  p[t + 256] = x1 * inv;
  p[t + 512] = x2 * inv;
}

// ---------------------------------------------------------------------------
extern "C" void kernel_launch(void* const* d_in, const int* in_sizes, int n_in,
                              void* d_out, int out_size, void* d_ws, size_t ws_size,
                              hipStream_t stream) {
  const float* phys  = (const float*)d_in[0];
  const float* proc  = (const float*)d_in[1];
  const float* micro = (const float*)d_in[2];
  const int*   pos   = (const int*)d_in[3];
  const float* W1    = (const float*)d_in[4];
  const float* b1    = (const float*)d_in[5];
  const float* W2    = (const float*)d_in[6];
  const float* b2    = (const float*)d_in[7];
  float* out = (float*)d_out;

  // ws layout (bf16): A1f | A2f | W1f | W2f  (~9.4 MB)
  __hip_bfloat16* A1f = (__hip_bfloat16*)d_ws;
  __hip_bfloat16* A2f = A1f + (size_t)32 * NK1 * 512;
  __hip_bfloat16* W1f = A2f + (size_t)32 * NK2 * 512;
  __hip_bfloat16* W2f = W1f + (size_t)48 * NK1 * 512;

  pool_cvt_kernel<<<2 * B_ + CVT_BLOCKS, 192, 0, stream>>>(
      phys, proc, micro, pos, W1, W2, A1f, A2f, W1f, W2f);
  gemm_mfma_kernel<<<192, 256, 0, stream>>>(
      A1f, A2f, W1f, W2f, b1, b2, out);
  norm_rows_kernel<<<2 * B_, 256, 0, stream>>>(out);
}